// Round 2
// baseline (670.812 us; speedup 1.0000x reference)
//
#include <hip/hip_runtime.h>
#include <hip/hip_bf16.h>

// CausalMixer: B=128, T=64, NA=10, NV=16, K=4, SD=512, H=256, E=32
// 8192 rows total. One block = 16 consecutive rows (same batch index b).
// Dtype of float tensors detected at runtime (f32 vs bf16); math in f32.

#define RPB 16
#define SDIM 512
#define HDIM 256
#define NAG 10
#define NVAR 16
#define KSEL 4
#define EMB 32

typedef __hip_bfloat16 bf16;

struct Smem {
  float s[RPB][516];     // states, f32, padded
  float buf[RPB][258];   // reused: h_base(pre-relu) -> m1 -> m2
  float hd[HDIM];        // h_delta
  float q[RPB][NAG];
  int   cr[RPB][66];     // (k*16+v), padded
  float w0c[RPB][4], w0s[RPB][4];
  float gq[RPB][17];
  float w01[RPB][NAG];
  float b01[RPB];
  float gb[RPB];
  float gd;
  float hid[RPB][EMB];
  float w2[RPB][EMB];
  float rb[RPB][EMB];
};

template <bool F32>
__device__ __forceinline__ float LD(const void* p, int i) {
  if (F32) return ((const float*)p)[i];
  return __bfloat162float(((const bf16*)p)[i]);
}

// 1 = float32, 0 = bf16. True-bf16 N(0,1) data has exponent fields in a sane
// band; f32 data read as ushorts has ~46% of words with wild exponents.
__global__ void detect_dtype_kernel(const void* __restrict__ states, int* __restrict__ flag) {
  if (threadIdx.x == 0 && blockIdx.x == 0) {
    const unsigned short* u = (const unsigned short*)states;
    int bad = 0;
    for (int i = 0; i < 512; ++i) {
      unsigned short x = u[i];
      int e = (x >> 7) & 0xFF;
      if (e > 140 || (((x & 0x7FFFu) != 0) && e < 100)) bad++;
    }
    *flag = (bad > 20) ? 1 : 0;
  }
}

template <bool F32>
__device__ void run_mixer(
    Smem& sm, int tid, int n0, int b_blk,
    const void* qvals, const int* crel, const void* states,
    const void* w00l1W, const void* w00l1b, const void* w00l2W, const void* w00l2b,
    const void* b00W, const void* b00b,
    const void* w01W, const void* w01b, const void* b01W, const void* b01b,
    const void* w1l1W, const void* w1l1b, const void* w1l2W, const void* w1l2b,
    const void* b1W, const void* b1b,
    const void* w2l1W, const void* w2l1b, const void* w2l2W, const void* w2l2b,
    const void* b2l1W, const void* b2l1b, const void* b2l2W, const void* b2l2b,
    void* out)
{
  // ---- P0: stage per-row inputs ----
  for (int idx = tid; idx < RPB * SDIM; idx += 256) {
    int r = idx >> 9, i = idx & 511;
    sm.s[r][i] = LD<F32>(states, (n0 + r) * SDIM + i);
  }
  for (int idx = tid; idx < RPB * NAG; idx += 256) {
    int r = idx / NAG, a = idx % NAG;
    sm.q[r][a] = LD<F32>(qvals, (n0 + r) * NAG + a);
  }
  for (int idx = tid; idx < RPB * 64; idx += 256) {
    int r = idx >> 6, kv = idx & 63;
    sm.cr[r][kv] = crel[(n0 + r) * 64 + kv];
  }
  if (tid == 0) {
    float gd = 0.f;
    for (int i = SDIM; i < SDIM + NVAR; ++i) gd += LD<F32>(b00W, i);
    sm.gd = gd;
  }
  __syncthreads();

  // ---- P1: h_base = states @ w00_l1_W[:512] + b (pre-relu); h_delta ----
  {
    const int j = tid;
    float hd = 0.f;
    for (int i = 0; i < NVAR; ++i) hd += LD<F32>(w00l1W, (SDIM + i) * HDIM + j);
    sm.hd[j] = hd;
    float acc[RPB];
    float bj = LD<F32>(w00l1b, j);
#pragma unroll
    for (int r = 0; r < RPB; ++r) acc[r] = bj;
    for (int i = 0; i < SDIM; ++i) {
      float w = LD<F32>(w00l1W, i * HDIM + j);
#pragma unroll
      for (int r = 0; r < RPB; ++r) acc[r] = fmaf(sm.s[r][i], w, acc[r]);
    }
#pragma unroll
    for (int r = 0; r < RPB; ++r) sm.buf[r][j] = acc[r];
  }
  __syncthreads();

  // ---- P2: w0 (common & special), w01 hypernet, g_base, b01 ----
  if (tid < 64) {
    int r = tid >> 2, k = tid & 3;
    float aC = 0.f, aS = 0.f;
    for (int j = 0; j < HDIM; ++j) {
      float hb = sm.buf[r][j];
      float w  = LD<F32>(w00l2W, j * 4 + k);
      float hc = hb > 0.f ? hb : 0.f;
      float hbs = hb + sm.hd[j];
      float hsv = hbs > 0.f ? hbs : 0.f;
      aC = fmaf(hc, w, aC);
      aS = fmaf(hsv, w, aS);
    }
    float bk = LD<F32>(w00l2b, k);
    sm.w0c[r][k] = aC + bk;
    sm.w0s[r][k] = aS + bk;
  } else if (tid < 224) {
    int p = tid - 64; int r = p / NAG, a = p % NAG;
    float acc = 0.f;
    for (int i = 0; i < SDIM; ++i) acc = fmaf(sm.s[r][i], LD<F32>(w01W, i * NAG + a), acc);
    sm.w01[r][a] = acc + LD<F32>(w01b, a);
  } else if (tid < 240) {
    int r = tid - 224;
    float acc = 0.f;
    for (int i = 0; i < SDIM; ++i) acc = fmaf(sm.s[r][i], LD<F32>(b00W, i), acc);
    sm.gb[r] = acc + LD<F32>(b00b, 0);
  } else {
    int r = tid - 240;
    float acc = 0.f;
    for (int i = 0; i < SDIM; ++i) acc = fmaf(sm.s[r][i], LD<F32>(b01W, i), acc);
    sm.b01[r] = acc + LD<F32>(b01b, 0);
  }
  __syncthreads();

  // ---- P3: group q-values + residual agent term -> gq (17 per row) ----
  {
    int r = tid >> 4, v = tid & 15;
    bool sp = (v == b_blk);
    const float* w0 = sp ? sm.w0s[r] : sm.w0c[r];
    float g = sm.gb[r] + (sp ? sm.gd : 0.f);
#pragma unroll
    for (int k = 0; k < KSEL; ++k) {
      int a = sm.cr[r][k * 16 + v];
      g = fmaf(sm.q[r][a], fabsf(w0[k]), g);
    }
    sm.gq[r][v] = g;
  }
  if (tid < RPB) {
    int r = tid;
    float o = sm.b01[r];
    for (int a = 0; a < NAG; ++a) o = fmaf(sm.q[r][a], sm.w01[r][a], o);
    sm.gq[r][16] = o;
  }
  __syncthreads();

  // ---- P4: m1 = relu(states @ w1_l1_W + b) ----
  {
    const int j = tid;
    float acc[RPB];
    float bj = LD<F32>(w1l1b, j);
#pragma unroll
    for (int r = 0; r < RPB; ++r) acc[r] = bj;
    for (int i = 0; i < SDIM; ++i) {
      float w = LD<F32>(w1l1W, i * HDIM + j);
#pragma unroll
      for (int r = 0; r < RPB; ++r) acc[r] = fmaf(sm.s[r][i], w, acc[r]);
    }
#pragma unroll
    for (int r = 0; r < RPB; ++r) sm.buf[r][j] = acc[r] > 0.f ? acc[r] : 0.f;
  }
  __syncthreads();

  // ---- P5: hidden = elu(sum_v gq_v * |w1[v,e]| + b1) ----
  for (int p = tid; p < RPB * EMB; p += 256) {
    int r = p >> 5, e = p & 31;
    float acc = 0.f;
    for (int v = 0; v < NVAR + 1; ++v) {
      int c = v * EMB + e;
      float d = LD<F32>(w1l2b, c);
      for (int j = 0; j < HDIM; ++j) d = fmaf(sm.buf[r][j], LD<F32>(w1l2W, j * 544 + c), d);
      acc = fmaf(sm.gq[r][v], fabsf(d), acc);
    }
    float b1v = LD<F32>(b1b, e);
    for (int i = 0; i < SDIM; ++i) b1v = fmaf(sm.s[r][i], LD<F32>(b1W, i * EMB + e), b1v);
    float x = acc + b1v;
    sm.hid[r][e] = x > 0.f ? x : (expf(x) - 1.f);
  }
  __syncthreads();

  // ---- P6: m2 = relu(states @ w2_l1_W + b) ----
  {
    const int j = tid;
    float acc[RPB];
    float bj = LD<F32>(w2l1b, j);
#pragma unroll
    for (int r = 0; r < RPB; ++r) acc[r] = bj;
    for (int i = 0; i < SDIM; ++i) {
      float w = LD<F32>(w2l1W, i * HDIM + j);
#pragma unroll
      for (int r = 0; r < RPB; ++r) acc[r] = fmaf(sm.s[r][i], w, acc[r]);
    }
#pragma unroll
    for (int r = 0; r < RPB; ++r) sm.buf[r][j] = acc[r] > 0.f ? acc[r] : 0.f;
  }
  __syncthreads();

  // ---- P7: w2 = |m2 @ w2_l2_W + b|, rb = relu(states @ b2_l1_W + b) ----
  for (int p = tid; p < RPB * EMB; p += 256) {
    int r = p >> 5, e = p & 31;
    float d = LD<F32>(w2l2b, e);
    for (int j = 0; j < HDIM; ++j) d = fmaf(sm.buf[r][j], LD<F32>(w2l2W, j * EMB + e), d);
    sm.w2[r][e] = fabsf(d);
    float rb = LD<F32>(b2l1b, e);
    for (int i = 0; i < SDIM; ++i) rb = fmaf(sm.s[r][i], LD<F32>(b2l1W, i * EMB + e), rb);
    sm.rb[r][e] = rb > 0.f ? rb : 0.f;
  }
  __syncthreads();

  // ---- P8: y = sum_e hidden*w2 + (rb @ b2_l2_W + b) ----
  if (tid < RPB) {
    int r = tid;
    float y = 0.f;
#pragma unroll
    for (int e = 0; e < EMB; ++e) y = fmaf(sm.hid[r][e], sm.w2[r][e], y);
    float b2v = LD<F32>(b2l2b, 0);
#pragma unroll
    for (int e = 0; e < EMB; ++e) b2v = fmaf(sm.rb[r][e], LD<F32>(b2l2W, e), b2v);
    float yv = y + b2v;
    if (F32) ((float*)out)[n0 + r] = yv;
    else     ((bf16*)out)[n0 + r] = __float2bfloat16(yv);
  }
}

__global__ __launch_bounds__(256) void causal_mixer_kernel(
    const void* qvals, const int* crel, const void* states,
    const void* w00l1W, const void* w00l1b, const void* w00l2W, const void* w00l2b,
    const void* b00W, const void* b00b,
    const void* w01W, const void* w01b, const void* b01W, const void* b01b,
    const void* w1l1W, const void* w1l1b, const void* w1l2W, const void* w1l2b,
    const void* b1W, const void* b1b,
    const void* w2l1W, const void* w2l1b, const void* w2l2W, const void* w2l2b,
    const void* b2l1W, const void* b2l1b, const void* b2l2W, const void* b2l2b,
    void* out, const int* flagp)
{
  __shared__ Smem sm;
  const int tid = threadIdx.x;
  const int n0  = blockIdx.x * RPB;
  const int b_blk = n0 >> 6;  // batch index shared by all 16 rows (16 | 64)
  if (*flagp) {
    run_mixer<true>(sm, tid, n0, b_blk, qvals, crel, states,
        w00l1W, w00l1b, w00l2W, w00l2b, b00W, b00b, w01W, w01b, b01W, b01b,
        w1l1W, w1l1b, w1l2W, w1l2b, b1W, b1b, w2l1W, w2l1b, w2l2W, w2l2b,
        b2l1W, b2l1b, b2l2W, b2l2b, out);
  } else {
    run_mixer<false>(sm, tid, n0, b_blk, qvals, crel, states,
        w00l1W, w00l1b, w00l2W, w00l2b, b00W, b00b, w01W, w01b, b01W, b01b,
        w1l1W, w1l1b, w1l2W, w1l2b, b1W, b1b, w2l1W, w2l1b, w2l2W, w2l2b,
        b2l1W, b2l1b, b2l2W, b2l2b, out);
  }
}

extern "C" void kernel_launch(void* const* d_in, const int* in_sizes, int n_in,
                              void* d_out, int out_size, void* d_ws, size_t ws_size,
                              hipStream_t stream) {
  int* flag = (int*)d_ws;
  hipLaunchKernelGGL(detect_dtype_kernel, dim3(1), dim3(64), 0, stream, d_in[2], flag);
  hipLaunchKernelGGL(causal_mixer_kernel, dim3(8192 / RPB), dim3(256), 0, stream,
      d_in[0], (const int*)d_in[1], d_in[2],
      d_in[3], d_in[4], d_in[5], d_in[6], d_in[7], d_in[8],
      d_in[9], d_in[10], d_in[11], d_in[12],
      d_in[13], d_in[14], d_in[15], d_in[16], d_in[17], d_in[18],
      d_in[19], d_in[20], d_in[21], d_in[22], d_in[23], d_in[24],
      d_in[25], d_in[26],
      d_out, flag);
}

// Round 3
// 247.146 us; speedup vs baseline: 2.7142x; 2.7142x over previous
//
#include <hip/hip_runtime.h>
#include <hip/hip_bf16.h>

// CausalMixer: B=128, T=64, NA=10, NV=16, K=4, SD=512, H=256, E=32. 8192 rows.
// MFMA path: prep kernel packs weights transposed (N x K, bf16) into d_ws;
// main kernel: block = 16 rows (one 16x16x32 M-tile), 4 waves, 2 MFMA phases
// + scalar epilogue. Fallback to scalar kernel if ws too small.

typedef __hip_bfloat16 bf16;
typedef unsigned short ushort_t;
typedef __attribute__((ext_vector_type(8))) short short8;
typedef __attribute__((ext_vector_type(4))) float f32x4;

#define WTA_OFF 256
#define WTA_ROWS 848
#define WTB_OFF (WTA_OFF + WTA_ROWS * 512 * 2)
#define WTB_ROWS 592
#define HD_OFF (WTB_OFF + WTB_ROWS * 256 * 2)
#define GD_OFF (HD_OFF + 256 * 4)
#define WS_NEED (size_t)(GD_OFF + 16)

#define MFMA16(a, b, c) __builtin_amdgcn_mfma_f32_16x16x32_bf16(a, b, c, 0, 0, 0)

__device__ __forceinline__ float us2f(ushort_t x) {
  unsigned u = ((unsigned)x) << 16; float f; __builtin_memcpy(&f, &u, 4); return f;
}
__device__ __forceinline__ ushort_t f2us(float v) {
  bf16 h = __float2bfloat16(v); ushort_t r; __builtin_memcpy(&r, &h, 2); return r;
}

template <bool F32>
__device__ __forceinline__ float LD(const void* p, int i) {
  if (F32) return ((const float*)p)[i];
  return us2f(((const ushort_t*)p)[i]);
}

// 1 = float32, 0 = bf16 (exponent-field heuristic on states)
__global__ void detect_dtype_kernel(const void* __restrict__ states, int* __restrict__ flag) {
  if (threadIdx.x == 0 && blockIdx.x == 0) {
    const unsigned short* u = (const unsigned short*)states;
    int bad = 0;
    for (int i = 0; i < 512; ++i) {
      unsigned short x = u[i];
      int e = (x >> 7) & 0xFF;
      if (e > 140 || (((x & 0x7FFFu) != 0) && e < 100)) bad++;
    }
    *flag = (bad > 20) ? 1 : 0;
  }
}

// ---------------- prep: pack transposed bf16 weights into ws ----------------
template <bool F32>
__device__ void prep_body(int gtid, int T, char* ws,
    const void* w00l1W, const void* b00W, const void* w01W, const void* b01W,
    const void* w1l1W, const void* w1l2W, const void* b1W,
    const void* w2l1W, const void* w2l2W, const void* b2l1W) {
  ushort_t* wta = (ushort_t*)(ws + WTA_OFF);
  ushort_t* wtb = (ushort_t*)(ws + WTB_OFF);
  float* hd = (float*)(ws + HD_OFF);
  float* gd = (float*)(ws + GD_OFF);
  for (int idx = gtid; idx < 512 * 256; idx += T) { int n = idx & 255, k = idx >> 8;
    wta[(size_t)n * 512 + k] = f2us(LD<F32>(w1l1W, k * 256 + n)); }
  for (int idx = gtid; idx < 512 * 256; idx += T) { int n = idx & 255, k = idx >> 8;
    wta[(size_t)(256 + n) * 512 + k] = f2us(LD<F32>(w2l1W, k * 256 + n)); }
  for (int idx = gtid; idx < 512 * 256; idx += T) { int n = idx & 255, k = idx >> 8;
    wta[(size_t)(512 + n) * 512 + k] = f2us(LD<F32>(w00l1W, k * 256 + n)); }
  for (int idx = gtid; idx < 512 * 32; idx += T) { int e = idx & 31, k = idx >> 5;
    wta[(size_t)(768 + e) * 512 + k] = f2us(LD<F32>(b1W, k * 32 + e)); }
  for (int idx = gtid; idx < 512 * 32; idx += T) { int e = idx & 31, k = idx >> 5;
    wta[(size_t)(800 + e) * 512 + k] = f2us(LD<F32>(b2l1W, k * 32 + e)); }
  for (int idx = gtid; idx < 512 * 10; idx += T) { int a = idx % 10, k = idx / 10;
    wta[(size_t)(832 + a) * 512 + k] = f2us(LD<F32>(w01W, k * 10 + a)); }
  for (int k = gtid; k < 512; k += T) {
    wta[(size_t)842 * 512 + k] = f2us(LD<F32>(b00W, k));
    wta[(size_t)843 * 512 + k] = f2us(LD<F32>(b01W, k)); }
  for (int idx = gtid; idx < 4 * 512; idx += T) wta[(size_t)844 * 512 + idx] = 0;
  for (int idx = gtid; idx < 256 * 544; idx += T) { int n = idx % 544, k = idx / 544;
    wtb[(size_t)n * 256 + k] = f2us(LD<F32>(w1l2W, k * 544 + n)); }
  for (int idx = gtid; idx < 256 * 32; idx += T) { int e = idx & 31, k = idx >> 5;
    wtb[(size_t)(544 + e) * 256 + k] = f2us(LD<F32>(w2l2W, k * 32 + e)); }
  for (int idx = gtid; idx < 16 * 256; idx += T) wtb[(size_t)576 * 256 + idx] = 0;
  if (gtid < 256) { float s = 0; for (int i = 0; i < 16; ++i) s += LD<F32>(w00l1W, (512 + i) * 256 + gtid); hd[gtid] = s; }
  if (gtid == 256) { float s = 0; for (int i = 0; i < 16; ++i) s += LD<F32>(b00W, 512 + i); *gd = s; }
}

__global__ __launch_bounds__(256) void prep_kernel(char* ws,
    const void* w00l1W, const void* b00W, const void* w01W, const void* b01W,
    const void* w1l1W, const void* w1l2W, const void* b1W,
    const void* w2l1W, const void* w2l2W, const void* b2l1W) {
  int gtid = blockIdx.x * 256 + threadIdx.x;
  int T = gridDim.x * 256;
  if (*(const int*)ws)
    prep_body<true>(gtid, T, ws, w00l1W, b00W, w01W, b01W, w1l1W, w1l2W, b1W, w2l1W, w2l2W, b2l1W);
  else
    prep_body<false>(gtid, T, ws, w00l1W, b00W, w01W, b01W, w1l1W, w1l2W, b1W, w2l1W, w2l2W, b2l1W);
}

// ---------------- main MFMA kernel ----------------
struct SmemM {
  union {
    __align__(16) ushort_t sA[16][520];   // states bf16 (phase A)
    ushort_t w1a[16][548];                // |w1 raw| bf16 (phase B+)
  } u;
  __align__(16) ushort_t Am1[16][264];    // relu(states@w1l1+b)
  __align__(16) ushort_t Am2[16][264];    // relu(states@w2l1+b)
  __align__(16) ushort_t hb[16][264];     // states@w00l1+b (pre-relu)
  float b1v[16][32];
  float rbv[16][32];
  float w2v[16][32];
  float w01v[16][12];
  float qv[16][10];
  unsigned char cr[16][64];
  float w0c[16][4], w0s[16][4];
  float gq[16][18];
  float gbv[16], b01v[16];
  float hid[16][33];
};

template <bool F32>
__device__ void mixer_body(SmemM& sm, const char* ws, int n0row,
    const void* qvals, const int* crel, const void* states,
    const void* w00l1b, const void* w00l2W, const void* w00l2b, const void* b00b,
    const void* w01b, const void* b01b,
    const void* w1l1b, const void* w1l2b, const void* b1b,
    const void* w2l1b, const void* w2l2b, const void* b2l1b,
    const void* b2l2W, const void* b2l2b, void* out) {
  const int tid = threadIdx.x;
  const int lane = tid & 63, wid = tid >> 6;
  const int q = lane >> 4, lm = lane & 15;
  const int b_blk = n0row >> 6;
  const ushort_t* wta = (const ushort_t*)(ws + WTA_OFF);
  const ushort_t* wtb = (const ushort_t*)(ws + WTB_OFF);
  const float* hdp = (const float*)(ws + HD_OFF);

  // stage inputs
  for (int idx = tid; idx < 16 * 512; idx += 256) {
    int r = idx >> 9, i = idx & 511;
    float v = LD<F32>(states, (n0row + r) * 512 + i);
    sm.u.sA[r][i] = f2us(v);
  }
  for (int idx = tid; idx < 160; idx += 256) {
    int r = idx / 10, a = idx % 10;
    sm.qv[r][a] = LD<F32>(qvals, (n0row + r) * 10 + a);
  }
  for (int idx = tid; idx < 16 * 64; idx += 256) {
    int r = idx >> 6, kv = idx & 63;
    sm.cr[r][kv] = (unsigned char)crel[(n0row + r) * 64 + kv];
  }
  __syncthreads();

  // A-fragments (states), shared by all tiles: A[m=lm][k = ks*32 + q*8 + j]
  short8 af[16];
#pragma unroll
  for (int ks = 0; ks < 16; ++ks)
    af[ks] = *(const short8*)&sm.u.sA[lm][ks * 32 + q * 8];

  // ---- Phase A: Y1 = S(16x512) @ WtA^T, tiles over N=848 ----
  for (int t = wid; t < 53; t += 4) {
    f32x4 acc = {0.f, 0.f, 0.f, 0.f};
    const ushort_t* bp = wta + (size_t)(t * 16 + lm) * 512 + q * 8;
#pragma unroll
    for (int ks = 0; ks < 16; ++ks) {
      short8 bf = *(const short8*)(bp + ks * 32);
      acc = MFMA16(af[ks], bf, acc);
    }
    int c = t * 16 + lm;
    if (c < 256) {
      float b = LD<F32>(w1l1b, c);
#pragma unroll
      for (int g = 0; g < 4; ++g) { float v = acc[g] + b; sm.Am1[q * 4 + g][c] = f2us(v > 0.f ? v : 0.f); }
    } else if (c < 512) {
      float b = LD<F32>(w2l1b, c - 256);
#pragma unroll
      for (int g = 0; g < 4; ++g) { float v = acc[g] + b; sm.Am2[q * 4 + g][c - 256] = f2us(v > 0.f ? v : 0.f); }
    } else if (c < 768) {
      float b = LD<F32>(w00l1b, c - 512);
#pragma unroll
      for (int g = 0; g < 4; ++g) sm.hb[q * 4 + g][c - 512] = f2us(acc[g] + b);
    } else if (c < 800) {
      float b = LD<F32>(b1b, c - 768);
#pragma unroll
      for (int g = 0; g < 4; ++g) sm.b1v[q * 4 + g][c - 768] = acc[g] + b;
    } else if (c < 832) {
      float b = LD<F32>(b2l1b, c - 800);
#pragma unroll
      for (int g = 0; g < 4; ++g) { float v = acc[g] + b; sm.rbv[q * 4 + g][c - 800] = v > 0.f ? v : 0.f; }
    } else if (c < 842) {
      float b = LD<F32>(w01b, c - 832);
#pragma unroll
      for (int g = 0; g < 4; ++g) sm.w01v[q * 4 + g][c - 832] = acc[g] + b;
    } else if (c == 842) {
      float b = LD<F32>(b00b, 0);
#pragma unroll
      for (int g = 0; g < 4; ++g) sm.gbv[q * 4 + g] = acc[g] + b;
    } else if (c == 843) {
      float b = LD<F32>(b01b, 0);
#pragma unroll
      for (int g = 0; g < 4; ++g) sm.b01v[q * 4 + g] = acc[g] + b;
    }
  }
  __syncthreads();

  // ---- Phase B: w1raw = m1 @ w1l2 (tiles 0..33), w2raw = m2 @ w2l2 (34,35) ----
  short8 m1f[8];
#pragma unroll
  for (int ks = 0; ks < 8; ++ks)
    m1f[ks] = *(const short8*)&sm.Am1[lm][ks * 32 + q * 8];
  short8 m2f[8];
  bool m2loaded = false;
  for (int t = wid; t < 36; t += 4) {
    const short8* usef = m1f;
    if (t >= 34) {
      if (!m2loaded) {
#pragma unroll
        for (int ks = 0; ks < 8; ++ks)
          m2f[ks] = *(const short8*)&sm.Am2[lm][ks * 32 + q * 8];
        m2loaded = true;
      }
      usef = m2f;
    }
    f32x4 acc = {0.f, 0.f, 0.f, 0.f};
    const ushort_t* bp = wtb + (size_t)(t * 16 + lm) * 256 + q * 8;
#pragma unroll
    for (int ks = 0; ks < 8; ++ks) {
      short8 bf = *(const short8*)(bp + ks * 32);
      acc = MFMA16(usef[ks], bf, acc);
    }
    int c = t * 16 + lm;
    if (c < 544) {
      float b = LD<F32>(w1l2b, c);
#pragma unroll
      for (int g = 0; g < 4; ++g) sm.u.w1a[q * 4 + g][c] = f2us(fabsf(acc[g] + b));
    } else {
      int e = c - 544;
      float b = LD<F32>(w2l2b, e);
#pragma unroll
      for (int g = 0; g < 4; ++g) sm.w2v[q * 4 + g][e] = fabsf(acc[g] + b);
    }
  }
  __syncthreads();

  // ---- C1: w0c/w0s = relu(hb[+hd]) @ w00l2 + b (scalar, 128 threads) ----
  if (tid < 128) {
    int r = tid >> 3, k = (tid >> 1) & 3, s = tid & 1;
    float a = 0.f;
    for (int j = 0; j < 256; ++j) {
      float h = us2f(sm.hb[r][j]);
      if (s) h += hdp[j];
      h = h > 0.f ? h : 0.f;
      a = fmaf(h, LD<F32>(w00l2W, j * 4 + k), a);
    }
    a += LD<F32>(w00l2b, k);
    if (s) sm.w0s[r][k] = a; else sm.w0c[r][k] = a;
  }
  __syncthreads();

  // ---- C2: gq ----
  {
    int r = tid >> 4, v = tid & 15;
    bool sp = (v == b_blk);
    float gdv = *(const float*)(ws + GD_OFF);
    const float* w0 = sp ? sm.w0s[r] : sm.w0c[r];
    float g = sm.gbv[r] + (sp ? gdv : 0.f);
#pragma unroll
    for (int k = 0; k < 4; ++k) {
      int a = sm.cr[r][k * 16 + v];
      g = fmaf(sm.qv[r][a], fabsf(w0[k]), g);
    }
    sm.gq[r][v] = g;
  }
  if (tid < 16) {
    int r = tid;
    float o = sm.b01v[r];
    for (int a = 0; a < 10; ++a) o = fmaf(sm.qv[r][a], sm.w01v[r][a], o);
    sm.gq[r][16] = o;
  }
  __syncthreads();

  // ---- C3: hidden = elu(sum_v gq*|w1| + b1); per (r,e) products ----
  for (int p = tid; p < 512; p += 256) {
    int r = p >> 5, e = p & 31;
    float h = sm.b1v[r][e];
#pragma unroll
    for (int v = 0; v < 17; ++v) h = fmaf(sm.gq[r][v], us2f(sm.u.w1a[r][v * 32 + e]), h);
    float hid = h > 0.f ? h : (expf(h) - 1.f);
    sm.hid[r][e] = hid * sm.w2v[r][e] + sm.rbv[r][e] * LD<F32>(b2l2W, e);
  }
  __syncthreads();

  // ---- C4: row reduce + store ----
  if (tid < 16) {
    int r = tid;
    float y = LD<F32>(b2l2b, 0);
#pragma unroll
    for (int e = 0; e < 32; ++e) y += sm.hid[r][e];
    if (F32) ((float*)out)[n0row + r] = y;
    else ((bf16*)out)[n0row + r] = __float2bfloat16(y);
  }
}

__global__ __launch_bounds__(256) void causal_mixer_mfma(const char* ws,
    const void* qvals, const int* crel, const void* states,
    const void* w00l1b, const void* w00l2W, const void* w00l2b, const void* b00b,
    const void* w01b, const void* b01b,
    const void* w1l1b, const void* w1l2b, const void* b1b,
    const void* w2l1b, const void* w2l2b, const void* b2l1b,
    const void* b2l2W, const void* b2l2b, void* out) {
  __shared__ SmemM sm;
  int n0row = blockIdx.x * 16;
  if (*(const int*)ws)
    mixer_body<true>(sm, ws, n0row, qvals, crel, states, w00l1b, w00l2W, w00l2b, b00b,
        w01b, b01b, w1l1b, w1l2b, b1b, w2l1b, w2l2b, b2l1b, b2l2W, b2l2b, out);
  else
    mixer_body<false>(sm, ws, n0row, qvals, crel, states, w00l1b, w00l2W, w00l2b, b00b,
        w01b, b01b, w1l1b, w1l2b, b1b, w2l1b, w2l2b, b2l1b, b2l2W, b2l2b, out);
}

// ---------------- fallback scalar kernel (round-2, proven) ----------------
struct SmemF {
  float s[16][516];
  float buf[16][258];
  float hd[256];
  float q[16][10];
  int cr[16][66];
  float w0c[16][4], w0s[16][4];
  float gq[16][17];
  float w01[16][10];
  float b01[16];
  float gb[16];
  float gd;
  float hid[16][32];
  float w2[16][32];
  float rb[16][32];
};

template <bool F32>
__device__ void fb_body(SmemF& sm, int tid, int n0, int b_blk,
    const void* qvals, const int* crel, const void* states,
    const void* w00l1W, const void* w00l1b, const void* w00l2W, const void* w00l2b,
    const void* b00W, const void* b00b,
    const void* w01W, const void* w01b, const void* b01W, const void* b01b,
    const void* w1l1W, const void* w1l1b, const void* w1l2W, const void* w1l2b,
    const void* b1W, const void* b1b,
    const void* w2l1W, const void* w2l1b, const void* w2l2W, const void* w2l2b,
    const void* b2l1W, const void* b2l1b, const void* b2l2W, const void* b2l2b,
    void* out) {
  for (int idx = tid; idx < 16 * 512; idx += 256) {
    int r = idx >> 9, i = idx & 511;
    sm.s[r][i] = LD<F32>(states, (n0 + r) * 512 + i);
  }
  for (int idx = tid; idx < 160; idx += 256) {
    int r = idx / 10, a = idx % 10;
    sm.q[r][a] = LD<F32>(qvals, (n0 + r) * 10 + a);
  }
  for (int idx = tid; idx < 16 * 64; idx += 256) {
    int r = idx >> 6, kv = idx & 63;
    sm.cr[r][kv] = crel[(n0 + r) * 64 + kv];
  }
  if (tid == 0) {
    float gd = 0.f;
    for (int i = 512; i < 528; ++i) gd += LD<F32>(b00W, i);
    sm.gd = gd;
  }
  __syncthreads();
  {
    const int j = tid;
    float hd = 0.f;
    for (int i = 0; i < 16; ++i) hd += LD<F32>(w00l1W, (512 + i) * 256 + j);
    sm.hd[j] = hd;
    float acc[16];
    float bj = LD<F32>(w00l1b, j);
#pragma unroll
    for (int r = 0; r < 16; ++r) acc[r] = bj;
    for (int i = 0; i < 512; ++i) {
      float w = LD<F32>(w00l1W, i * 256 + j);
#pragma unroll
      for (int r = 0; r < 16; ++r) acc[r] = fmaf(sm.s[r][i], w, acc[r]);
    }
#pragma unroll
    for (int r = 0; r < 16; ++r) sm.buf[r][j] = acc[r];
  }
  __syncthreads();
  if (tid < 64) {
    int r = tid >> 2, k = tid & 3;
    float aC = 0.f, aS = 0.f;
    for (int j = 0; j < 256; ++j) {
      float hb = sm.buf[r][j];
      float w = LD<F32>(w00l2W, j * 4 + k);
      float hc = hb > 0.f ? hb : 0.f;
      float hbs = hb + sm.hd[j];
      float hsv = hbs > 0.f ? hbs : 0.f;
      aC = fmaf(hc, w, aC);
      aS = fmaf(hsv, w, aS);
    }
    float bk = LD<F32>(w00l2b, k);
    sm.w0c[r][k] = aC + bk;
    sm.w0s[r][k] = aS + bk;
  } else if (tid < 224) {
    int p = tid - 64; int r = p / 10, a = p % 10;
    float acc = 0.f;
    for (int i = 0; i < 512; ++i) acc = fmaf(sm.s[r][i], LD<F32>(w01W, i * 10 + a), acc);
    sm.w01[r][a] = acc + LD<F32>(w01b, a);
  } else if (tid < 240) {
    int r = tid - 224;
    float acc = 0.f;
    for (int i = 0; i < 512; ++i) acc = fmaf(sm.s[r][i], LD<F32>(b00W, i), acc);
    sm.gb[r] = acc + LD<F32>(b00b, 0);
  } else {
    int r = tid - 240;
    float acc = 0.f;
    for (int i = 0; i < 512; ++i) acc = fmaf(sm.s[r][i], LD<F32>(b01W, i), acc);
    sm.b01[r] = acc + LD<F32>(b01b, 0);
  }
  __syncthreads();
  {
    int r = tid >> 4, v = tid & 15;
    bool sp = (v == b_blk);
    const float* w0 = sp ? sm.w0s[r] : sm.w0c[r];
    float g = sm.gb[r] + (sp ? sm.gd : 0.f);
#pragma unroll
    for (int k = 0; k < 4; ++k) {
      int a = sm.cr[r][k * 16 + v];
      g = fmaf(sm.q[r][a], fabsf(w0[k]), g);
    }
    sm.gq[r][v] = g;
  }
  if (tid < 16) {
    int r = tid;
    float o = sm.b01[r];
    for (int a = 0; a < 10; ++a) o = fmaf(sm.q[r][a], sm.w01[r][a], o);
    sm.gq[r][16] = o;
  }
  __syncthreads();
  {
    const int j = tid;
    float acc[16];
    float bj = LD<F32>(w1l1b, j);
#pragma unroll
    for (int r = 0; r < 16; ++r) acc[r] = bj;
    for (int i = 0; i < 512; ++i) {
      float w = LD<F32>(w1l1W, i * 256 + j);
#pragma unroll
      for (int r = 0; r < 16; ++r) acc[r] = fmaf(sm.s[r][i], w, acc[r]);
    }
#pragma unroll
    for (int r = 0; r < 16; ++r) sm.buf[r][j] = acc[r] > 0.f ? acc[r] : 0.f;
  }
  __syncthreads();
  for (int p = tid; p < 512; p += 256) {
    int r = p >> 5, e = p & 31;
    float acc = 0.f;
    for (int v = 0; v < 17; ++v) {
      int c = v * 32 + e;
      float d = LD<F32>(w1l2b, c);
      for (int j = 0; j < 256; ++j) d = fmaf(sm.buf[r][j], LD<F32>(w1l2W, j * 544 + c), d);
      acc = fmaf(sm.gq[r][v], fabsf(d), acc);
    }
    float b1v = LD<F32>(b1b, e);
    for (int i = 0; i < 512; ++i) b1v = fmaf(sm.s[r][i], LD<F32>(b1W, i * 32 + e), b1v);
    float x = acc + b1v;
    sm.hid[r][e] = x > 0.f ? x : (expf(x) - 1.f);
  }
  __syncthreads();
  {
    const int j = tid;
    float acc[16];
    float bj = LD<F32>(w2l1b, j);
#pragma unroll
    for (int r = 0; r < 16; ++r) acc[r] = bj;
    for (int i = 0; i < 512; ++i) {
      float w = LD<F32>(w2l1W, i * 256 + j);
#pragma unroll
      for (int r = 0; r < 16; ++r) acc[r] = fmaf(sm.s[r][i], w, acc[r]);
    }
#pragma unroll
    for (int r = 0; r < 16; ++r) sm.buf[r][j] = acc[r] > 0.f ? acc[r] : 0.f;
  }
  __syncthreads();
  for (int p = tid; p < 512; p += 256) {
    int r = p >> 5, e = p & 31;
    float d = LD<F32>(w2l2b, e);
    for (int j = 0; j < 256; ++j) d = fmaf(sm.buf[r][j], LD<F32>(w2l2W, j * 32 + e), d);
    sm.w2[r][e] = fabsf(d);
    float rb = LD<F32>(b2l1b, e);
    for (int i = 0; i < 512; ++i) rb = fmaf(sm.s[r][i], LD<F32>(b2l1W, i * 32 + e), rb);
    sm.rb[r][e] = rb > 0.f ? rb : 0.f;
  }
  __syncthreads();
  if (tid < 16) {
    int r = tid;
    float y = 0.f;
#pragma unroll
    for (int e = 0; e < 32; ++e) y = fmaf(sm.hid[r][e], sm.w2[r][e], y);
    float b2v = LD<F32>(b2l2b, 0);
#pragma unroll
    for (int e = 0; e < 32; ++e) b2v = fmaf(sm.rb[r][e], LD<F32>(b2l2W, e), b2v);
    float yv = y + b2v;
    if (F32) ((float*)out)[n0 + r] = yv;
    else ((bf16*)out)[n0 + r] = __float2bfloat16(yv);
  }
}

__global__ __launch_bounds__(256) void causal_mixer_fb(
    const void* qvals, const int* crel, const void* states,
    const void* w00l1W, const void* w00l1b, const void* w00l2W, const void* w00l2b,
    const void* b00W, const void* b00b,
    const void* w01W, const void* w01b, const void* b01W, const void* b01b,
    const void* w1l1W, const void* w1l1b, const void* w1l2W, const void* w1l2b,
    const void* b1W, const void* b1b,
    const void* w2l1W, const void* w2l1b, const void* w2l2W, const void* w2l2b,
    const void* b2l1W, const void* b2l1b, const void* b2l2W, const void* b2l2b,
    void* out, const int* flagp) {
  __shared__ SmemF sm;
  const int tid = threadIdx.x;
  const int n0 = blockIdx.x * 16;
  const int b_blk = n0 >> 6;
  if (*flagp)
    fb_body<true>(sm, tid, n0, b_blk, qvals, crel, states, w00l1W, w00l1b, w00l2W, w00l2b,
        b00W, b00b, w01W, w01b, b01W, b01b, w1l1W, w1l1b, w1l2W, w1l2b, b1W, b1b,
        w2l1W, w2l1b, w2l2W, w2l2b, b2l1W, b2l1b, b2l2W, b2l2b, out);
  else
    fb_body<false>(sm, tid, n0, b_blk, qvals, crel, states, w00l1W, w00l1b, w00l2W, w00l2b,
        b00W, b00b, w01W, w01b, b01W, b01b, w1l1W, w1l1b, w1l2W, w1l2b, b1W, b1b,
        w2l1W, w2l1b, w2l2W, w2l2b, b2l1W, b2l1b, b2l2W, b2l2b, out);
}

extern "C" void kernel_launch(void* const* d_in, const int* in_sizes, int n_in,
                              void* d_out, int out_size, void* d_ws, size_t ws_size,
                              hipStream_t stream) {
  char* ws = (char*)d_ws;
  hipLaunchKernelGGL(detect_dtype_kernel, dim3(1), dim3(64), 0, stream, d_in[2], (int*)ws);
  if (ws_size >= WS_NEED) {
    hipLaunchKernelGGL(prep_kernel, dim3(512), dim3(256), 0, stream, ws,
        d_in[3], d_in[7], d_in[9], d_in[11],
        d_in[13], d_in[15], d_in[17],
        d_in[19], d_in[21], d_in[23]);
    hipLaunchKernelGGL(causal_mixer_mfma, dim3(512), dim3(256), 0, stream, ws,
        d_in[0], (const int*)d_in[1], d_in[2],
        d_in[4], d_in[5], d_in[6], d_in[8],
        d_in[10], d_in[12],
        d_in[14], d_in[16], d_in[18],
        d_in[20], d_in[22], d_in[24],
        d_in[25], d_in[26], d_out);
  } else {
    hipLaunchKernelGGL(causal_mixer_fb, dim3(512), dim3(256), 0, stream,
        d_in[0], (const int*)d_in[1], d_in[2],
        d_in[3], d_in[4], d_in[5], d_in[6], d_in[7], d_in[8],
        d_in[9], d_in[10], d_in[11], d_in[12],
        d_in[13], d_in[14], d_in[15], d_in[16], d_in[17], d_in[18],
        d_in[19], d_in[20], d_in[21], d_in[22], d_in[23], d_in[24],
        d_in[25], d_in[26],
        d_out, (const int*)ws);
  }
}

// Round 4
// 170.297 us; speedup vs baseline: 3.9391x; 1.4513x over previous
//
#include <hip/hip_runtime.h>
#include <hip/hip_bf16.h>

// CausalMixer: B=128, T=64, NA=10, NV=16, K=4, SD=512, H=256, E=32. 8192 rows.
// prep packs weights bf16 pre-swizzled into MFMA lane order (1KB/wave-load)
// + all biases as f32 into d_ws. Main: block = 16 rows, 512 thr (8 waves),
// per-wave 2-tile N-panels, K-chunk loop, 2 indep MFMA chains.

typedef __hip_bfloat16 bf16;
typedef unsigned short ushort_t;
typedef __attribute__((ext_vector_type(8))) short short8;
typedef __attribute__((ext_vector_type(4))) float f32x4;

#define PA_OFF 256
#define PA_TILES 56              // 896 cols padded
#define PB_OFF (PA_OFF + PA_TILES * 16 * 1024)          // 917760
#define PB_TILES 36              // 576 cols
#define FB_OFF (PB_OFF + PB_TILES * 8 * 1024)           // 1212672
#define NCST 2854
#define WS_NEED (size_t)(FB_OFF + NCST * 4 + 64)

#define MFMA16(a, b, c) __builtin_amdgcn_mfma_f32_16x16x32_bf16(a, b, c, 0, 0, 0)

__device__ __forceinline__ float us2f(ushort_t x) {
  unsigned u = ((unsigned)x) << 16; float f; __builtin_memcpy(&f, &u, 4); return f;
}
__device__ __forceinline__ ushort_t f2us(float v) {
  bf16 h = __float2bfloat16(v); ushort_t r; __builtin_memcpy(&r, &h, 2); return r;
}
template <bool F32>
__device__ __forceinline__ float LD(const void* p, int i) {
  if (F32) return ((const float*)p)[i];
  return us2f(((const ushort_t*)p)[i]);
}

// 1 = float32, 0 = bf16 (exponent-field heuristic on states)
__global__ void detect_dtype_kernel(const void* __restrict__ states, int* __restrict__ flag) {
  int tid = threadIdx.x;
  const unsigned short* u = (const unsigned short*)states;
  int bad = 0;
  for (int i = tid; i < 512; i += 64) {
    unsigned short x = u[i];
    int e = (x >> 7) & 0xFF;
    if (e > 140 || (((x & 0x7FFFu) != 0) && e < 100)) bad++;
  }
  for (int off = 32; off; off >>= 1) bad += __shfl_down(bad, off);
  if (tid == 0) *flag = (bad > 20) ? 1 : 0;
}

// ---------------- prep: pack swizzled bf16 weights + f32 consts ----------------
template <bool F32>
__device__ void prep_body(int gtid, int T, char* ws,
    const void* w00l1W, const void* w00l1b, const void* w00l2W, const void* w00l2b,
    const void* b00W, const void* b00b,
    const void* w01W, const void* w01b, const void* b01W, const void* b01b,
    const void* w1l1W, const void* w1l1b, const void* w1l2W, const void* w1l2b,
    const void* b1W, const void* b1b,
    const void* w2l1W, const void* w2l1b, const void* w2l2W, const void* w2l2b,
    const void* b2l1W, const void* b2l1b, const void* b2l2W, const void* b2l2b) {
  ushort_t* pa = (ushort_t*)(ws + PA_OFF);
  ushort_t* pb = (ushort_t*)(ws + PB_OFF);
  float* cst = (float*)(ws + FB_OFF);
  // phase-A pack: 56 tiles x 16 ks x 64 lanes, 8 bf16 each (one 16B store)
  for (int o = gtid; o < PA_TILES * 16 * 64; o += T) {
    int lane = o & 63, ks = (o >> 6) & 15, t = o >> 10;
    int lm = lane & 15, qq = lane >> 4;
    int n = t * 16 + lm, kbase = ks * 32 + qq * 8;
    ushort_t v[8];
#pragma unroll
    for (int j = 0; j < 8; ++j) {
      int k = kbase + j; float x;
      if (n < 256) x = LD<F32>(w1l1W, k * 256 + n);
      else if (n < 512) x = LD<F32>(w2l1W, k * 256 + n - 256);
      else if (n < 768) x = LD<F32>(w00l1W, k * 256 + n - 512);
      else if (n < 800) x = LD<F32>(b1W, k * 32 + n - 768);
      else if (n < 832) x = LD<F32>(b2l1W, k * 32 + n - 800);
      else if (n < 842) x = LD<F32>(w01W, k * 10 + n - 832);
      else if (n == 842) x = LD<F32>(b00W, k);
      else if (n == 843) x = LD<F32>(b01W, k);
      else x = 0.f;
      v[j] = f2us(x);
    }
    *(short8*)(pa + (size_t)o * 8) = *(short8*)v;
  }
  // phase-B pack: 36 tiles x 8 ks x 64 lanes
  for (int o = gtid; o < PB_TILES * 8 * 64; o += T) {
    int lane = o & 63, ks = (o >> 6) & 7, t = o >> 9;
    int lm = lane & 15, qq = lane >> 4;
    int n = t * 16 + lm, kbase = ks * 32 + qq * 8;
    ushort_t v[8];
#pragma unroll
    for (int j = 0; j < 8; ++j) {
      int k = kbase + j;
      float x = (n < 544) ? LD<F32>(w1l2W, k * 544 + n) : LD<F32>(w2l2W, k * 32 + n - 544);
      v[j] = f2us(x);
    }
    *(short8*)(pb + (size_t)o * 8) = *(short8*)v;
  }
  // f32 consts: biasA[896] biasB[640] hd[256] w00l2W[1024] w00l2b[4] b2l2W[32] b2l2b gd
  for (int i = gtid; i < NCST; i += T) {
    float x;
    if (i < 896) {
      int c = i;
      if (c < 256) x = LD<F32>(w1l1b, c);
      else if (c < 512) x = LD<F32>(w2l1b, c - 256);
      else if (c < 768) x = LD<F32>(w00l1b, c - 512);
      else if (c < 800) x = LD<F32>(b1b, c - 768);
      else if (c < 832) x = LD<F32>(b2l1b, c - 800);
      else if (c < 842) x = LD<F32>(w01b, c - 832);
      else if (c == 842) x = LD<F32>(b00b, 0);
      else if (c == 843) x = LD<F32>(b01b, 0);
      else x = 0.f;
    } else if (i < 1536) {
      int c = i - 896;
      x = (c < 544) ? LD<F32>(w1l2b, c) : (c < 576 ? LD<F32>(w2l2b, c - 544) : 0.f);
    } else if (i < 1792) {
      int j = i - 1536; float s = 0.f;
      for (int z = 0; z < 16; ++z) s += LD<F32>(w00l1W, (512 + z) * 256 + j);
      x = s;
    } else if (i < 2816) x = LD<F32>(w00l2W, i - 1792);
    else if (i < 2820) x = LD<F32>(w00l2b, i - 2816);
    else if (i < 2852) x = LD<F32>(b2l2W, i - 2820);
    else if (i == 2852) x = LD<F32>(b2l2b, 0);
    else { float s = 0.f; for (int z = 0; z < 16; ++z) s += LD<F32>(b00W, 512 + z); x = s; }
    cst[i] = x;
  }
}

__global__ __launch_bounds__(256) void prep_kernel(char* ws,
    const void* w00l1W, const void* w00l1b, const void* w00l2W, const void* w00l2b,
    const void* b00W, const void* b00b,
    const void* w01W, const void* w01b, const void* b01W, const void* b01b,
    const void* w1l1W, const void* w1l1b, const void* w1l2W, const void* w1l2b,
    const void* b1W, const void* b1b,
    const void* w2l1W, const void* w2l1b, const void* w2l2W, const void* w2l2b,
    const void* b2l1W, const void* b2l1b, const void* b2l2W, const void* b2l2b) {
  int gtid = blockIdx.x * 256 + threadIdx.x;
  int T = gridDim.x * 256;
  if (*(const int*)ws)
    prep_body<true>(gtid, T, ws, w00l1W, w00l1b, w00l2W, w00l2b, b00W, b00b,
        w01W, w01b, b01W, b01b, w1l1W, w1l1b, w1l2W, w1l2b, b1W, b1b,
        w2l1W, w2l1b, w2l2W, w2l2b, b2l1W, b2l1b, b2l2W, b2l2b);
  else
    prep_body<false>(gtid, T, ws, w00l1W, w00l1b, w00l2W, w00l2b, b00W, b00b,
        w01W, w01b, b01W, b01b, w1l1W, w1l1b, w1l2W, w1l2b, b1W, b1b,
        w2l1W, w2l1b, w2l2W, w2l2b, b2l1W, b2l1b, b2l2W, b2l2b);
}

// ---------------- main MFMA kernel ----------------
// cst layout: biasA@0, biasB@896, hd@1536, w00l2W@1792, w00l2b@2816,
//             b2l2W@2820, b2l2b@2852, gd@2853
struct SmemM {
  union {
    __align__(16) ushort_t sA[16][520];   // states bf16 (phase A)
    __align__(16) ushort_t w1a[16][548];  // |w1 raw| bf16 (phase B+)
  } u;
  __align__(16) ushort_t Am1[16][264];
  __align__(16) ushort_t Am2[16][264];
  __align__(16) ushort_t hb[16][264];
  __align__(16) float cst[NCST];
  float b1v[16][32];
  float rbv[16][32];
  float w2v[16][32];
  float w01v[16][12];
  float qv[16][10];
  unsigned char cr[16][64];
  float w0c[16][4], w0s[16][4];
  float gq[16][18];
  float gbv[16], b01v[16];
  float hid[16][33];
};

struct F4 { float x, y, z, w; };

template <bool F32>
__device__ void mixer_body(SmemM& sm, const char* ws, int n0,
    const void* qvals, const int* crel, const void* states, void* out) {
  const int tid = threadIdx.x;              // 0..511
  const int lane = tid & 63, wv = tid >> 6; // 8 waves
  const int q = lane >> 4, lm = lane & 15;
  const int b_blk = n0 >> 6;
  const ushort_t* pa = (const ushort_t*)(ws + PA_OFF);
  const ushort_t* pb = (const ushort_t*)(ws + PB_OFF);
  const float* fsrc = (const float*)(ws + FB_OFF);

  // ---- stage ----
  if (F32) {
    const F4* st4 = (const F4*)states;
    for (int fi = tid; fi < 2048; fi += 512) {
      int r = fi >> 7, c4 = fi & 127;
      F4 v = st4[(size_t)(n0 + r) * 128 + c4];
      ushort_t* dst = &sm.u.sA[r][c4 * 4];
      dst[0] = f2us(v.x); dst[1] = f2us(v.y); dst[2] = f2us(v.z); dst[3] = f2us(v.w);
    }
  } else {
    for (int fi = tid; fi < 1024; fi += 512) {
      int r = fi >> 6, c8 = fi & 63;
      *(short8*)&sm.u.sA[r][c8 * 8] =
          *(const short8*)((const ushort_t*)states + (size_t)(n0 + r) * 512 + c8 * 8);
    }
  }
  for (int i = tid; i < 160; i += 512) sm.qv[i / 10][i % 10] = LD<F32>(qvals, (n0 + i / 10) * 10 + i % 10);
  for (int i = tid; i < 1024; i += 512) sm.cr[i >> 6][i & 63] = (unsigned char)crel[n0 * 64 + i];
  for (int i = tid; i < NCST; i += 512) sm.cst[i] = fsrc[i];
  __syncthreads();

  // ---- Phase A: Y = S(16x512) @ WtA, 56 N-tiles in 28 2-tile panels ----
  for (int p = wv; p < 28; p += 8) {
    int t0 = 2 * p;
    const ushort_t* b0 = pa + (size_t)t0 * 8192 + lane * 8;
    f32x4 acc0 = {0.f, 0.f, 0.f, 0.f}, acc1 = {0.f, 0.f, 0.f, 0.f};
#pragma unroll
    for (int ks = 0; ks < 16; ++ks) {
      short8 a = *(const short8*)&sm.u.sA[lm][ks * 32 + q * 8];
      short8 f0 = *(const short8*)(b0 + ks * 512);
      short8 f1 = *(const short8*)(b0 + 8192 + ks * 512);
      acc0 = MFMA16(a, f0, acc0);
      acc1 = MFMA16(a, f1, acc1);
    }
#pragma unroll
    for (int h = 0; h < 2; ++h) {
      f32x4 acc = h ? acc1 : acc0;
      int c = (t0 + h) * 16 + lm;
      if (c >= 844) continue;
      float bias = sm.cst[c];
      int rb = q * 4;
      if (c < 256) {
#pragma unroll
        for (int g = 0; g < 4; ++g) { float v = acc[g] + bias; sm.Am1[rb + g][c] = f2us(v > 0.f ? v : 0.f); }
      } else if (c < 512) {
#pragma unroll
        for (int g = 0; g < 4; ++g) { float v = acc[g] + bias; sm.Am2[rb + g][c - 256] = f2us(v > 0.f ? v : 0.f); }
      } else if (c < 768) {
#pragma unroll
        for (int g = 0; g < 4; ++g) sm.hb[rb + g][c - 512] = f2us(acc[g] + bias);
      } else if (c < 800) {
#pragma unroll
        for (int g = 0; g < 4; ++g) sm.b1v[rb + g][c - 768] = acc[g] + bias;
      } else if (c < 832) {
#pragma unroll
        for (int g = 0; g < 4; ++g) { float v = acc[g] + bias; sm.rbv[rb + g][c - 800] = v > 0.f ? v : 0.f; }
      } else if (c < 842) {
#pragma unroll
        for (int g = 0; g < 4; ++g) sm.w01v[rb + g][c - 832] = acc[g] + bias;
      } else if (c == 842) {
#pragma unroll
        for (int g = 0; g < 4; ++g) sm.gbv[rb + g] = acc[g] + bias;
      } else {
#pragma unroll
        for (int g = 0; g < 4; ++g) sm.b01v[rb + g] = acc[g] + bias;
      }
    }
  }
  __syncthreads();

  // ---- Phase B: 36 N-tiles (w1l2 0..33 from m1; w2l2 34..35 from m2) ----
  for (int p = wv; p < 18; p += 8) {
    int t0 = 2 * p;
    const ushort_t* arow = (t0 < 34) ? sm.Am1[lm] : sm.Am2[lm];
    const ushort_t* b0 = pb + (size_t)t0 * 4096 + lane * 8;
    f32x4 acc0 = {0.f, 0.f, 0.f, 0.f}, acc1 = {0.f, 0.f, 0.f, 0.f};
#pragma unroll
    for (int ks = 0; ks < 8; ++ks) {
      short8 a = *(const short8*)(arow + ks * 32 + q * 8);
      short8 f0 = *(const short8*)(b0 + ks * 512);
      short8 f1 = *(const short8*)(b0 + 4096 + ks * 512);
      acc0 = MFMA16(a, f0, acc0);
      acc1 = MFMA16(a, f1, acc1);
    }
#pragma unroll
    for (int h = 0; h < 2; ++h) {
      f32x4 acc = h ? acc1 : acc0;
      int c = (t0 + h) * 16 + lm;
      float bias = sm.cst[896 + c];
      int rb = q * 4;
      if (c < 544) {
#pragma unroll
        for (int g = 0; g < 4; ++g) sm.u.w1a[rb + g][c] = f2us(fabsf(acc[g] + bias));
      } else {
        int e = c - 544;
#pragma unroll
        for (int g = 0; g < 4; ++g) sm.w2v[rb + g][e] = fabsf(acc[g] + bias);
      }
    }
  }
  __syncthreads();

  // ---- C1: w0c/w0s = relu(hb [+hd]) @ w00l2 + b ----
  if (tid < 128) {
    int r = tid >> 3, k = (tid >> 1) & 3, s = tid & 1;
    const float* w2l = sm.cst + 1792;
    float a = 0.f;
    for (int j = 0; j < 256; ++j) {
      float h = us2f(sm.hb[r][j]);
      if (s) h += sm.cst[1536 + j];
      h = h > 0.f ? h : 0.f;
      a = fmaf(h, w2l[j * 4 + k], a);
    }
    a += sm.cst[2816 + k];
    if (s) sm.w0s[r][k] = a; else sm.w0c[r][k] = a;
  }
  __syncthreads();

  // ---- C2: gq ----
  if (tid < 256) {
    int r = tid >> 4, v = tid & 15;
    bool sp = (v == b_blk);
    const float* w0 = sp ? sm.w0s[r] : sm.w0c[r];
    float g = sm.gbv[r] + (sp ? sm.cst[2853] : 0.f);
#pragma unroll
    for (int k = 0; k < 4; ++k) {
      int a = sm.cr[r][k * 16 + v];
      g = fmaf(sm.qv[r][a], fabsf(w0[k]), g);
    }
    sm.gq[r][v] = g;
  } else if (tid < 272) {
    int r = tid - 256;
    float o = sm.b01v[r];
#pragma unroll
    for (int a = 0; a < 10; ++a) o = fmaf(sm.qv[r][a], sm.w01v[r][a], o);
    sm.gq[r][16] = o;
  }
  __syncthreads();

  // ---- C3: hidden = elu(sum_v gq*|w1|+b1); fuse *w2 + rb*b2l2W ----
  {
    int r = tid >> 5, e = tid & 31;
    float h = sm.b1v[r][e];
#pragma unroll
    for (int v = 0; v < 17; ++v) h = fmaf(sm.gq[r][v], us2f(sm.u.w1a[r][v * 32 + e]), h);
    float hid = h > 0.f ? h : (expf(h) - 1.f);
    sm.hid[r][e] = hid * sm.w2v[r][e] + sm.rbv[r][e] * sm.cst[2820 + e];
  }
  __syncthreads();

  // ---- C4: row reduce + store ----
  if (tid < 16) {
    float y = sm.cst[2852];
#pragma unroll
    for (int e = 0; e < 32; ++e) y += sm.hid[tid][e];
    if (F32) ((float*)out)[n0 + tid] = y;
    else ((bf16*)out)[n0 + tid] = __float2bfloat16(y);
  }
}

__global__ __launch_bounds__(512, 4) void causal_mixer_mfma(const char* ws,
    const void* qvals, const int* crel, const void* states, void* out) {
  __shared__ SmemM sm;
  int n0 = blockIdx.x * 16;
  if (*(const int*)ws)
    mixer_body<true>(sm, ws, n0, qvals, crel, states, out);
  else
    mixer_body<false>(sm, ws, n0, qvals, crel, states, out);
}

// ---------------- fallback scalar kernel (round-2, proven) ----------------
struct SmemF {
  float s[16][516]; float buf[16][258]; float hd[256];
  float q[16][10]; int cr[16][66];
  float w0c[16][4], w0s[16][4]; float gq[16][17];
  float w01[16][10]; float b01[16]; float gb[16]; float gd;
  float hid[16][32]; float w2[16][32]; float rb[16][32];
};

template <bool F32>
__device__ void fb_body(SmemF& sm, int tid, int n0, int b_blk,
    const void* qvals, const int* crel, const void* states,
    const void* w00l1W, const void* w00l1b, const void* w00l2W, const void* w00l2b,
    const void* b00W, const void* b00b,
    const void* w01W, const void* w01b, const void* b01W, const void* b01b,
    const void* w1l1W, const void* w1l1b, const void* w1l2W, const void* w1l2b,
    const void* b1W, const void* b1b,
    const void* w2l1W, const void* w2l1b, const void* w2l2W, const void* w2l2b,
    const void* b2l1W, const void* b2l1b, const void* b2l2W, const void* b2l2b,
    void* out) {
  for (int idx = tid; idx < 16 * 512; idx += 256) {
    int r = idx >> 9, i = idx & 511;
    sm.s[r][i] = LD<F32>(states, (n0 + r) * 512 + i);
  }
  for (int idx = tid; idx < 160; idx += 256) {
    int r = idx / 10, a = idx % 10;
    sm.q[r][a] = LD<F32>(qvals, (n0 + r) * 10 + a);
  }
  for (int idx = tid; idx < 16 * 64; idx += 256) {
    int r = idx >> 6, kv = idx & 63;
    sm.cr[r][kv] = crel[(n0 + r) * 64 + kv];
  }
  if (tid == 0) {
    float gd = 0.f;
    for (int i = 512; i < 528; ++i) gd += LD<F32>(b00W, i);
    sm.gd = gd;
  }
  __syncthreads();
  {
    const int j = tid;
    float hd = 0.f;
    for (int i = 0; i < 16; ++i) hd += LD<F32>(w00l1W, (512 + i) * 256 + j);
    sm.hd[j] = hd;
    float acc[16]; float bj = LD<F32>(w00l1b, j);
#pragma unroll
    for (int r = 0; r < 16; ++r) acc[r] = bj;
    for (int i = 0; i < 512; ++i) {
      float w = LD<F32>(w00l1W, i * 256 + j);
#pragma unroll
      for (int r = 0; r < 16; ++r) acc[r] = fmaf(sm.s[r][i], w, acc[r]);
    }
#pragma unroll
    for (int r = 0; r < 16; ++r) sm.buf[r][j] = acc[r];
  }
  __syncthreads();
  if (tid < 64) {
    int r = tid >> 2, k = tid & 3;
    float aC = 0.f, aS = 0.f;
    for (int j = 0; j < 256; ++j) {
      float hb = sm.buf[r][j];
      float w = LD<F32>(w00l2W, j * 4 + k);
      float hc = hb > 0.f ? hb : 0.f;
      float hbs = hb + sm.hd[j];
      float hsv = hbs > 0.f ? hbs : 0.f;
      aC = fmaf(hc, w, aC); aS = fmaf(hsv, w, aS);
    }
    float bk = LD<F32>(w00l2b, k);
    sm.w0c[r][k] = aC + bk; sm.w0s[r][k] = aS + bk;
  } else if (tid < 224) {
    int p = tid - 64; int r = p / 10, a = p % 10;
    float acc = 0.f;
    for (int i = 0; i < 512; ++i) acc = fmaf(sm.s[r][i], LD<F32>(w01W, i * 10 + a), acc);
    sm.w01[r][a] = acc + LD<F32>(w01b, a);
  } else if (tid < 240) {
    int r = tid - 224;
    float acc = 0.f;
    for (int i = 0; i < 512; ++i) acc = fmaf(sm.s[r][i], LD<F32>(b00W, i), acc);
    sm.gb[r] = acc + LD<F32>(b00b, 0);
  } else {
    int r = tid - 240;
    float acc = 0.f;
    for (int i = 0; i < 512; ++i) acc = fmaf(sm.s[r][i], LD<F32>(b01W, i), acc);
    sm.b01[r] = acc + LD<F32>(b01b, 0);
  }
  __syncthreads();
  {
    int r = tid >> 4, v = tid & 15;
    bool sp = (v == b_blk);
    const float* w0 = sp ? sm.w0s[r] : sm.w0c[r];
    float g = sm.gb[r] + (sp ? sm.gd : 0.f);
#pragma unroll
    for (int k = 0; k < 4; ++k) {
      int a = sm.cr[r][k * 16 + v];
      g = fmaf(sm.q[r][a], fabsf(w0[k]), g);
    }
    sm.gq[r][v] = g;
  }
  if (tid < 16) {
    int r = tid;
    float o = sm.b01[r];
    for (int a = 0; a < 10; ++a) o = fmaf(sm.q[r][a], sm.w01[r][a], o);
    sm.gq[r][16] = o;
  }
  __syncthreads();
  {
    const int j = tid;
    float acc[16]; float bj = LD<F32>(w1l1b, j);
#pragma unroll
    for (int r = 0; r < 16; ++r) acc[r] = bj;
    for (int i = 0; i < 512; ++i) {
      float w = LD<F32>(w1l1W, i * 256 + j);
#pragma unroll
      for (int r = 0; r < 16; ++r) acc[r] = fmaf(sm.s[r][i], w, acc[r]);
    }
#pragma unroll
    for (int r = 0; r < 16; ++r) sm.buf[r][j] = acc[r] > 0.f ? acc[r] : 0.f;
  }
  __syncthreads();
  for (int p = tid; p < 512; p += 256) {
    int r = p >> 5, e = p & 31;
    float acc = 0.f;
    for (int v = 0; v < 17; ++v) {
      int c = v * 32 + e;
      float d = LD<F32>(w1l2b, c);
      for (int j = 0; j < 256; ++j) d = fmaf(sm.buf[r][j], LD<F32>(w1l2W, j * 544 + c), d);
      acc = fmaf(sm.gq[r][v], fabsf(d), acc);
    }
    float b1v = LD<F32>(b1b, e);
    for (int i = 0; i < 512; ++i) b1v = fmaf(sm.s[r][i], LD<F32>(b1W, i * 32 + e), b1v);
    float x = acc + b1v;
    sm.hid[r][e] = x > 0.f ? x : (expf(x) - 1.f);
  }
  __syncthreads();
  {
    const int j = tid;
    float acc[16]; float bj = LD<F32>(w2l1b, j);
#pragma unroll
    for (int r = 0; r < 16; ++r) acc[r] = bj;
    for (int i = 0; i < 512; ++i) {
      float w = LD<F32>(w2l1W, i * 256 + j);
#pragma unroll
      for (int r = 0; r < 16; ++r) acc[r] = fmaf(sm.s[r][i], w, acc[r]);
    }
#pragma unroll
    for (int r = 0; r < 16; ++r) sm.buf[r][j] = acc[r] > 0.f ? acc[r] : 0.f;
  }
  __syncthreads();
  for (int p = tid; p < 512; p += 256) {
    int r = p >> 5, e = p & 31;
    float d = LD<F32>(w2l2b, e);
    for (int j = 0; j < 256; ++j) d = fmaf(sm.buf[r][j], LD<F32>(w2l2W, j * 32 + e), d);
    sm.w2[r][e] = fabsf(d);
    float rb = LD<F32>(b2l1b, e);
    for (int i = 0; i < 512; ++i) rb = fmaf(sm.s[r][i], LD<F32>(b2l1W, i * 32 + e), rb);
    sm.rb[r][e] = rb > 0.f ? rb : 0.f;
  }
  __syncthreads();
  if (tid < 16) {
    int r = tid;
    float y = 0.f;
#pragma unroll
    for (int e = 0; e < 32; ++e) y = fmaf(sm.hid[r][e], sm.w2[r][e], y);
    float b2v = LD<F32>(b2l2b, 0);
#pragma unroll
    for (int e = 0; e < 32; ++e) b2v = fmaf(sm.rb[r][e], LD<F32>(b2l2W, e), b2v);
    float yv = y + b2v;
    if (F32) ((float*)out)[n0 + r] = yv;
    else ((bf16*)out)[n0 + r] = __float2bfloat16(yv);
  }
}

__global__ __launch_bounds__(256) void causal_mixer_fb(
    const void* qvals, const int* crel, const void* states,
    const void* w00l1W, const void* w00l1b, const void* w00l2W, const void* w00l2b,
    const void* b00W, const void* b00b,
    const void* w01W, const void* w01b, const void* b01W, const void* b01b,
    const void* w1l1W, const void* w1l1b, const void* w1l2W, const void* w1l2b,
    const void* b1W, const void* b1b,
    const void* w2l1W, const void* w2l1b, const void* w2l2W, const void* w2l2b,
    const void* b2l1W, const void* b2l1b, const void* b2l2W, const void* b2l2b,
    void* out, const int* flagp) {
  __shared__ SmemF sm;
  const int tid = threadIdx.x;
  const int n0 = blockIdx.x * 16;
  const int b_blk = n0 >> 6;
  if (*flagp)
    fb_body<true>(sm, tid, n0, b_blk, qvals, crel, states, w00l1W, w00l1b, w00l2W, w00l2b,
        b00W, b00b, w01W, w01b, b01W, b01b, w1l1W, w1l1b, w1l2W, w1l2b, b1W, b1b,
        w2l1W, w2l1b, w2l2W, w2l2b, b2l1W, b2l1b, b2l2W, b2l2b, out);
  else
    fb_body<false>(sm, tid, n0, b_blk, qvals, crel, states, w00l1W, w00l1b, w00l2W, w00l2b,
        b00W, b00b, w01W, w01b, b01W, b01b, w1l1W, w1l1b, w1l2W, w1l2b, b1W, b1b,
        w2l1W, w2l1b, w2l2W, w2l2b, b2l1W, b2l1b, b2l2W, b2l2b, out);
}

extern "C" void kernel_launch(void* const* d_in, const int* in_sizes, int n_in,
                              void* d_out, int out_size, void* d_ws, size_t ws_size,
                              hipStream_t stream) {
  char* ws = (char*)d_ws;
  hipLaunchKernelGGL(detect_dtype_kernel, dim3(1), dim3(64), 0, stream, d_in[2], (int*)ws);
  if (ws_size >= WS_NEED) {
    hipLaunchKernelGGL(prep_kernel, dim3(256), dim3(256), 0, stream, ws,
        d_in[3], d_in[4], d_in[5], d_in[6], d_in[7], d_in[8],
        d_in[9], d_in[10], d_in[11], d_in[12],
        d_in[13], d_in[14], d_in[15], d_in[16], d_in[17], d_in[18],
        d_in[19], d_in[20], d_in[21], d_in[22], d_in[23], d_in[24],
        d_in[25], d_in[26]);
    hipLaunchKernelGGL(causal_mixer_mfma, dim3(512), dim3(512), 0, stream, ws,
        d_in[0], (const int*)d_in[1], d_in[2], d_out);
  } else {
    hipLaunchKernelGGL(causal_mixer_fb, dim3(512), dim3(256), 0, stream,
        d_in[0], (const int*)d_in[1], d_in[2],
        d_in[3], d_in[4], d_in[5], d_in[6], d_in[7], d_in[8],
        d_in[9], d_in[10], d_in[11], d_in[12],
        d_in[13], d_in[14], d_in[15], d_in[16], d_in[17], d_in[18],
        d_in[19], d_in[20], d_in[21], d_in[22], d_in[23], d_in[24],
        d_in[25], d_in[26],
        d_out, (const int*)ws);
  }
}